// Round 7
// baseline (682.531 us; speedup 1.0000x reference)
//
#include <hip/hip_runtime.h>
#include <hip/hip_cooperative_groups.h>

namespace cg = cooperative_groups;

#define IN_F 256
#define OUT_F 64
#define BKT_BITS 8           // 256 nodes per bucket
#define BKT_NODES 256
#define BKT_CAP 6656         // mean cnt 4096 (sigma 64) + pad mean ~900 -> +20 sigma margin
#define CHUNK 2048           // edges per block for binning pass (782 blocks -> full CU fill)
#define SRC_BITS 18          // N < 262144
#define SRC_MASK 0x3FFFF
#define SPMM_BLOCKS 1024     // cooperative grid: 4 blocks/CU guaranteed resident

typedef __attribute__((ext_vector_type(8))) short short8;    // 8 bf16 (4 VGPRs) — MFMA A/B frag
typedef __attribute__((ext_vector_type(4))) float floatx4;   // MFMA C/D frag
typedef __attribute__((ext_vector_type(4))) int intx4;       // 2 edges per 16B load

static __device__ __forceinline__ short f2bf_rne(float f) {
    unsigned u = __float_as_uint(f);
    unsigned r = (u + 0x7fffu + ((u >> 16) & 1u)) >> 16;  // round-nearest-even
    return (short)r;
}
static __device__ __forceinline__ float bf2f(short s) {
    return __uint_as_float(((unsigned)(unsigned short)s) << 16);
}

// ---------------- CSR build, pass 1: bin into fixed-capacity dst-buckets ----------------
// Block-local LDS hist -> one global atomic reservation per (block,bucket) -> short
// contiguous runs per region, all from ONE block/XCD so the bucket window merges in that
// XCD's L2 (direct global scatter loses 8x here, R1 lesson).
// binned[bkt*BKT_CAP + i].x = (dst_offset_in_bucket << SRC_BITS) | src, .y = w bits.
__global__ __launch_bounds__(256) void bin_kernel(const int* __restrict__ src,
                                                  const int* __restrict__ dst,
                                                  const float* __restrict__ w,
                                                  int* __restrict__ bkt_cnt,
                                                  int2* __restrict__ binned, int E, int nbkt) {
    __shared__ int h[512];           // nbkt = 391 <= 512
    int t = threadIdx.x;
    h[t] = 0;
    h[t + 256] = 0;
    __syncthreads();
    int base = blockIdx.x * CHUNK;
#pragma unroll
    for (int j = 0; j < CHUNK / 256; ++j) {
        int e = base + j * 256 + t;
        if (e < E) atomicAdd(&h[__builtin_nontemporal_load(dst + e) >> BKT_BITS], 1);
    }
    __syncthreads();
    int c0 = h[t], c1 = h[t + 256];
    int r0 = 0, r1 = 0;
    if (t < nbkt && c0) r0 = atomicAdd(&bkt_cnt[t], c0);
    if (t + 256 < nbkt && c1) r1 = atomicAdd(&bkt_cnt[t + 256], c1);
    __syncthreads();
    h[t] = r0;       // becomes block-local cursor (offset within bucket region)
    h[t + 256] = r1;
    __syncthreads();
#pragma unroll
    for (int j = 0; j < CHUNK / 256; ++j) {
        int e = base + j * 256 + t;
        if (e < E) {
            int d = dst[e];
            int bb = d >> BKT_BITS;
            int pos = atomicAdd(&h[bb], 1);
            binned[(size_t)bb * BKT_CAP + pos] =
                make_int2(((d & (BKT_NODES - 1)) << SRC_BITS) | src[e], __float_as_int(w[e]));
        }
    }
}

// ---------------- CSR build, pass 2 (fused): per-bucket count + padded scan + place + pad --
// Node slot counts rounded up to a multiple of 8 (pads = src 0, w 0) so spmm has no
// remainder. Bucket base is the static b*BKT_CAP; per-node (beg,end) packed in one int2
// so spmm fetches both with a single s_load_dwordx2.
__global__ __launch_bounds__(256) void build_bucket_kernel(const int2* __restrict__ binned,
                                                           const int* __restrict__ bkt_cnt,
                                                           int2* __restrict__ bego,
                                                           int2* __restrict__ edges,
                                                           int N) {
    __shared__ int h[BKT_NODES];   // per-node counts, then cursors
    __shared__ int ssum[256];
    int t = threadIdx.x;
    int b = blockIdx.x;
    h[t] = 0;
    __syncthreads();
    int cntb = bkt_cnt[b];
    const int2* bsrc = binned + (size_t)b * BKT_CAP;
    for (int e = t; e < cntb; e += 256) atomicAdd(&h[bsrc[e].x >> SRC_BITS], 1);
    __syncthreads();
    int c = h[t];
    int p = (c + 7) & ~7;          // padded slot count
    ssum[t] = p;
    __syncthreads();
    for (int off = 1; off < 256; off <<= 1) {
        int v = (t >= off) ? ssum[t - off] : 0;
        __syncthreads();
        ssum[t] += v;
        __syncthreads();
    }
    int base = b * BKT_CAP + (t > 0 ? ssum[t - 1] : 0);
    int node = (b << BKT_BITS) + t;
    if (node < N) bego[node] = make_int2(base, base + p);
    __syncthreads();  // all reads of h-as-counts done
    h[t] = base;
    __syncthreads();
    for (int e = t; e < cntb; e += 256) {
        int2 v = bsrc[e];
        int pos = atomicAdd(&h[v.x >> SRC_BITS], 1);
        edges[pos] = make_int2(v.x & SRC_MASK, v.y);
    }
    __syncthreads();  // cursors final: base + exact count
    for (int k = h[t]; k < base + p; ++k) edges[k] = make_int2(0, 0);
}

// ---------------- prep: W -> bf16 hi/lo MFMA B-fragments (blocks 0-7) + zero (blocks 8-9) --
__global__ void prep_kernel(const float* __restrict__ W,
                            short* __restrict__ bh, short* __restrict__ bl,
                            int* __restrict__ bkt_cnt, int nbkt) {
    int blk = blockIdx.x;
    if (blk >= 8) {
        int i = (blk - 8) * 256 + threadIdx.x;
        if (i < nbkt) bkt_cnt[i] = 0;
        return;
    }
    int t = blk * 256 + threadIdx.x;
    int combo = t >> 6;
    int lane = t & 63;
    int s = combo >> 2;
    int tO = combo & 3;
    int n = 16 * tO + (lane & 15);
    int k0 = 32 * s + (lane >> 4) * 8;
    const float* src = W + (size_t)n * IN_F + k0;
    short* dh = bh + (size_t)t * 8;
    short* dl = bl + (size_t)t * 8;
#pragma unroll
    for (int j = 0; j < 8; ++j) {
        float v = src[j];
        short h = f2bf_rne(v);
        dh[j] = h;
        dl[j] = f2bf_rne(v - bf2f(h));
    }
}

// ---------------- GEMM via MFMA bf16x3 ----------------
__global__ __launch_bounds__(256) void gemm_kernel(const float* __restrict__ x,
                                                   const short8* __restrict__ bh,
                                                   const short8* __restrict__ bl,
                                                   const float* __restrict__ b,
                                                   float* __restrict__ out, int N) {
    int lane = threadIdx.x & 63;
    int wid = threadIdx.x >> 6;
    int node0 = blockIdx.x * 64 + wid * 16;
    if (node0 >= N) return;
    if (node0 + 16 > N) node0 = N - 16;
    int m = lane & 15;
    int q = lane >> 4;

    // x is a pure 102MB stream with zero reuse: nontemporal keeps L2 for everything else
    const floatx4* xr = (const floatx4*)(x + (size_t)(node0 + m) * IN_F) + q * 2;

    floatx4 acc[4];
#pragma unroll
    for (int tO = 0; tO < 4; ++tO) acc[tO] = (floatx4){0.f, 0.f, 0.f, 0.f};

#pragma unroll
    for (int s = 0; s < 8; ++s) {
        floatx4 v0 = __builtin_nontemporal_load(xr + s * 8);
        floatx4 v1 = __builtin_nontemporal_load(xr + s * 8 + 1);
        float vv[8] = {v0[0], v0[1], v0[2], v0[3], v1[0], v1[1], v1[2], v1[3]};
        short8 ah, al;
#pragma unroll
        for (int j = 0; j < 8; ++j) {
            short h = f2bf_rne(vv[j]);
            ah[j] = h;
            al[j] = f2bf_rne(vv[j] - bf2f(h));
        }
#pragma unroll
        for (int tO = 0; tO < 4; ++tO) {
            short8 wh = bh[(s * 4 + tO) * 64 + lane];
            short8 wl = bl[(s * 4 + tO) * 64 + lane];
            acc[tO] = __builtin_amdgcn_mfma_f32_16x16x32_bf16(ah, wh, acc[tO], 0, 0, 0);
            acc[tO] = __builtin_amdgcn_mfma_f32_16x16x32_bf16(al, wh, acc[tO], 0, 0, 0);
            acc[tO] = __builtin_amdgcn_mfma_f32_16x16x32_bf16(ah, wl, acc[tO], 0, 0, 0);
        }
    }

#pragma unroll
    for (int tO = 0; tO < 4; ++tO) {
        float bias = b[16 * tO + m];
#pragma unroll
        for (int r = 0; r < 4; ++r) {
            out[(size_t)(node0 + q * 4 + r) * OUT_F + 16 * tO + m] = acc[tO][r] + bias;
        }
    }
}

// ---------------- SpMM gather core: sum_e w[e]*in[src[e]][lane] over one node's list ------
// Padded deg distribution: {8: 2%, 16: 53%, 24: 43%, >=32: 1.5%}. Single-shot gather paths
// for 8/16/24 (all gathers in flight, zero inter-batch drain); generic 16-loop otherwise.
// Edge loads as intx4 (2 edges / 16B instr; lists 64B-aligned by construction).
#define GATHER_Q(NB)                                                                     \
    {                                                                                    \
        intx4 Q[NB];                                                                     \
        float v[2 * NB];                                                                 \
        _Pragma("unroll") for (int j = 0; j < NB; ++j)                                   \
            Q[j] = __builtin_nontemporal_load(eq + j);                                   \
        _Pragma("unroll") for (int j = 0; j < NB; ++j) {                                 \
            v[2 * j]     = in[(size_t)Q[j][0] * OUT_F + lane];                           \
            v[2 * j + 1] = in[(size_t)Q[j][2] * OUT_F + lane];                           \
        }                                                                                \
        _Pragma("unroll") for (int j = 0; j < NB; ++j) {                                 \
            acc = fmaf(__int_as_float(Q[j][1]), v[2 * j], acc);                          \
            acc = fmaf(__int_as_float(Q[j][3]), v[2 * j + 1], acc);                      \
        }                                                                                \
    }

static __device__ __forceinline__ float spmm_node(const int2* __restrict__ edges,
                                                  const float* __restrict__ in,
                                                  int lane, int e, int end) {
    float acc = 0.f;
    int deg = end - e;
    const intx4* eq = (const intx4*)(edges + e);
    if (deg == 16) {
        GATHER_Q(8)
    } else if (deg == 24) {
        GATHER_Q(12)
    } else if (deg == 8) {
        GATHER_Q(4)
    } else {
        while (e + 16 <= end) {
            GATHER_Q(8)
            e += 16;
            eq = (const intx4*)(edges + e);
        }
        if (e < end) {   // exactly 8 remain (padded to multiple of 8)
            GATHER_Q(4)
        }
    }
    return acc;
}

// ---------------- SpMM x3 hops, cooperative (grid.sync between hops) ----------------
// One dispatch for all 3 hops: removes 2 kernel-boundary drains/launches and makes the
// spmm total directly visible in the profile. Grid = 1024 blocks (4/CU, 16 waves/CU
// guaranteed resident at VGPR<=128 via launch_bounds). Same wave->node map every hop.
__global__ __launch_bounds__(256, 4) void spmm3_kernel(const int2* __restrict__ bego,
                                                       const int2* __restrict__ edges,
                                                       float* __restrict__ buf0,
                                                       float* __restrict__ out, int N) {
    cg::grid_group grid = cg::this_grid();
    int gwave = __builtin_amdgcn_readfirstlane((blockIdx.x * blockDim.x + threadIdx.x) >> 6);
    int lane = threadIdx.x & 63;
    int nwaves = (gridDim.x * blockDim.x) >> 6;
#pragma unroll
    for (int hop = 0; hop < 3; ++hop) {
        const float* in = (hop == 1) ? out : buf0;
        float* o = (hop == 1) ? buf0 : out;
        for (int node = gwave; node < N; node += nwaves) {
            int2 be = bego[node];            // wave-uniform -> s_load_dwordx2
            float acc = spmm_node(edges, in, lane, be.x, be.y);
            __builtin_nontemporal_store(acc, o + (size_t)node * OUT_F + lane);
        }
        if (hop < 2) grid.sync();
    }
}

// ---------------- launch ----------------
extern "C" void kernel_launch(void* const* d_in, const int* in_sizes, int n_in,
                              void* d_out, int out_size, void* d_ws, size_t ws_size,
                              hipStream_t stream) {
    const float* x = (const float*)d_in[0];
    const float* W = (const float*)d_in[1];
    const float* b = (const float*)d_in[2];
    const int* esrc = (const int*)d_in[3];
    const int* edst = (const int*)d_in[4];
    const float* ew = (const float*)d_in[5];
    float* out = (float*)d_out;

    int N = in_sizes[0] / IN_F;
    int E = in_sizes[3];
    int nbkt = (N + BKT_NODES - 1) >> BKT_BITS;   // 391 for N=100000 (must be <= 512)

    char* ws = (char*)d_ws;
    size_t off = 0;
    float* buf0 = (float*)(ws + off);    off += (size_t)N * OUT_F * sizeof(float);
    int2* edges = (int2*)(ws + off);     off += (size_t)nbkt * BKT_CAP * sizeof(int2);
    int2* bego = (int2*)(ws + off);      off += (size_t)N * sizeof(int2);
    int* bkt_cnt = (int*)(ws + off);     off += 1024 * sizeof(int);
    short* bh = (short*)(ws + off);      off += 32 * 64 * 8 * sizeof(short);
    short* bl = (short*)(ws + off);      off += 32 * 64 * 8 * sizeof(short);
    // binned aliases buf0's region (391*6656*8B = 20.8MB <= 25.6MB): buf0 is only
    // written by gemm, which runs after build_bucket_kernel consumed binned.
    int2* binned = (int2*)buf0;
    (void)ws_size; (void)n_in; (void)out_size;

    int nb_chunk = (E + CHUNK - 1) / CHUNK;   // 782 blocks

    // prep (W frags + zero) and CSR build
    prep_kernel<<<10, 256, 0, stream>>>(W, bh, bl, bkt_cnt, nbkt);
    bin_kernel<<<nb_chunk, 256, 0, stream>>>(esrc, edst, ew, bkt_cnt, binned, E, nbkt);
    build_bucket_kernel<<<nbkt, 256, 0, stream>>>(binned, bkt_cnt, bego, edges, N);

    // projection
    gemm_kernel<<<(N + 63) / 64, 256, 0, stream>>>(x, (const short8*)bh, (const short8*)bl,
                                                   b, buf0, N);

    // 3 hops in one cooperative dispatch (buf0 -> out -> buf0 -> out)
    void* args[5] = {(void*)&bego, (void*)&edges, (void*)&buf0, (void*)&out, (void*)&N};
    hipLaunchCooperativeKernel((const void*)spmm3_kernel, dim3(SPMM_BLOCKS), dim3(256),
                               args, 0, stream);
}

// Round 8
// 348.357 us; speedup vs baseline: 1.9593x; 1.9593x over previous
//
#include <hip/hip_runtime.h>

#define IN_F 256
#define OUT_F 64
#define BKT_BITS 8           // 256 nodes per bucket
#define BKT_NODES 256
#define BKT_CAP 6656         // mean cnt 4096 (sigma 64) + pad mean ~900 -> +20 sigma margin
#define CHUNK 2048           // edges per block for binning pass (782 blocks)
#define SRC_BITS 18          // N < 262144
#define SRC_MASK 0x3FFFF

typedef __attribute__((ext_vector_type(8))) short short8;    // 8 bf16 (4 VGPRs) — MFMA A/B frag
typedef __attribute__((ext_vector_type(4))) float floatx4;   // MFMA C/D frag
typedef __attribute__((ext_vector_type(4))) int intx4;       // 2 edges per 16B load

static __device__ __forceinline__ short f2bf_rne(float f) {
    unsigned u = __float_as_uint(f);
    unsigned r = (u + 0x7fffu + ((u >> 16) & 1u)) >> 16;  // round-nearest-even
    return (short)r;
}
static __device__ __forceinline__ float bf2f(short s) {
    return __uint_as_float(((unsigned)(unsigned short)s) << 16);
}
static __device__ __forceinline__ float bfu2f(unsigned short s) {
    return __uint_as_float(((unsigned)s) << 16);
}

// ---------------- CSR build, pass 1: bin into fixed-capacity dst-buckets ----------------
// Block-local LDS hist -> one global atomic reservation per (block,bucket) -> short
// contiguous runs per region, all from ONE block/XCD so the bucket window merges in that
// XCD's L2 (direct global scatter loses 8x here, R1 lesson).
__global__ __launch_bounds__(256) void bin_kernel(const int* __restrict__ src,
                                                  const int* __restrict__ dst,
                                                  const float* __restrict__ w,
                                                  int* __restrict__ bkt_cnt,
                                                  int2* __restrict__ binned, int E, int nbkt) {
    __shared__ int h[512];           // nbkt = 391 <= 512
    int t = threadIdx.x;
    h[t] = 0;
    h[t + 256] = 0;
    __syncthreads();
    int base = blockIdx.x * CHUNK;
#pragma unroll
    for (int j = 0; j < CHUNK / 256; ++j) {
        int e = base + j * 256 + t;
        if (e < E) atomicAdd(&h[__builtin_nontemporal_load(dst + e) >> BKT_BITS], 1);
    }
    __syncthreads();
    int c0 = h[t], c1 = h[t + 256];
    int r0 = 0, r1 = 0;
    if (t < nbkt && c0) r0 = atomicAdd(&bkt_cnt[t], c0);
    if (t + 256 < nbkt && c1) r1 = atomicAdd(&bkt_cnt[t + 256], c1);
    __syncthreads();
    h[t] = r0;       // becomes block-local cursor (offset within bucket region)
    h[t + 256] = r1;
    __syncthreads();
#pragma unroll
    for (int j = 0; j < CHUNK / 256; ++j) {
        int e = base + j * 256 + t;
        if (e < E) {
            int d = dst[e];
            int bb = d >> BKT_BITS;
            int pos = atomicAdd(&h[bb], 1);
            binned[(size_t)bb * BKT_CAP + pos] =
                make_int2(((d & (BKT_NODES - 1)) << SRC_BITS) | src[e], __float_as_int(w[e]));
        }
    }
}

// ---------------- CSR build, pass 2 (fused): per-bucket count + padded scan + place + pad --
// Node slot counts rounded to a multiple of 8 (pads = src 0, w 0) so spmm has no remainder.
__global__ __launch_bounds__(256) void build_bucket_kernel(const int2* __restrict__ binned,
                                                           const int* __restrict__ bkt_cnt,
                                                           int2* __restrict__ bego,
                                                           int2* __restrict__ edges,
                                                           int N) {
    __shared__ int h[BKT_NODES];   // per-node counts, then cursors
    __shared__ int ssum[256];
    int t = threadIdx.x;
    int b = blockIdx.x;
    h[t] = 0;
    __syncthreads();
    int cntb = bkt_cnt[b];
    const int2* bsrc = binned + (size_t)b * BKT_CAP;
    for (int e = t; e < cntb; e += 256) atomicAdd(&h[bsrc[e].x >> SRC_BITS], 1);
    __syncthreads();
    int c = h[t];
    int p = (c + 7) & ~7;          // padded slot count
    ssum[t] = p;
    __syncthreads();
    for (int off = 1; off < 256; off <<= 1) {
        int v = (t >= off) ? ssum[t - off] : 0;
        __syncthreads();
        ssum[t] += v;
        __syncthreads();
    }
    int base = b * BKT_CAP + (t > 0 ? ssum[t - 1] : 0);
    int node = (b << BKT_BITS) + t;
    if (node < N) bego[node] = make_int2(base, base + p);
    __syncthreads();  // all reads of h-as-counts done
    h[t] = base;
    __syncthreads();
    for (int e = t; e < cntb; e += 256) {
        int2 v = bsrc[e];
        int pos = atomicAdd(&h[v.x >> SRC_BITS], 1);
        edges[pos] = make_int2(v.x & SRC_MASK, v.y);
    }
    __syncthreads();  // cursors final: base + exact count
    for (int k = h[t]; k < base + p; ++k) edges[k] = make_int2(0, 0);
}

// ---------------- prep: W -> bf16 hi/lo MFMA B-fragments (blocks 0-7) + zero (blocks 8-9) --
__global__ void prep_kernel(const float* __restrict__ W,
                            short* __restrict__ bh, short* __restrict__ bl,
                            int* __restrict__ bkt_cnt, int nbkt) {
    int blk = blockIdx.x;
    if (blk >= 8) {
        int i = (blk - 8) * 256 + threadIdx.x;
        if (i < nbkt) bkt_cnt[i] = 0;
        return;
    }
    int t = blk * 256 + threadIdx.x;
    int combo = t >> 6;
    int lane = t & 63;
    int s = combo >> 2;
    int tO = combo & 3;
    int n = 16 * tO + (lane & 15);
    int k0 = 32 * s + (lane >> 4) * 8;
    const float* src = W + (size_t)n * IN_F + k0;
    short* dh = bh + (size_t)t * 8;
    short* dl = bl + (size_t)t * 8;
#pragma unroll
    for (int j = 0; j < 8; ++j) {
        float v = src[j];
        short h = f2bf_rne(v);
        dh[j] = h;
        dl[j] = f2bf_rne(v - bf2f(h));
    }
}

// ---------------- GEMM via MFMA bf16x3; output rows stored as bf16 (128B/row) ----------
__global__ __launch_bounds__(256) void gemm_kernel(const float* __restrict__ x,
                                                   const short8* __restrict__ bh,
                                                   const short8* __restrict__ bl,
                                                   const float* __restrict__ b,
                                                   unsigned short* __restrict__ obf, int N) {
    int lane = threadIdx.x & 63;
    int wid = threadIdx.x >> 6;
    int node0 = blockIdx.x * 64 + wid * 16;
    if (node0 >= N) return;
    if (node0 + 16 > N) node0 = N - 16;
    int m = lane & 15;
    int q = lane >> 4;

    // x is a pure 102MB stream with zero reuse: nontemporal keeps L2 for everything else
    const floatx4* xr = (const floatx4*)(x + (size_t)(node0 + m) * IN_F) + q * 2;

    floatx4 acc[4];
#pragma unroll
    for (int tO = 0; tO < 4; ++tO) acc[tO] = (floatx4){0.f, 0.f, 0.f, 0.f};

#pragma unroll
    for (int s = 0; s < 8; ++s) {
        floatx4 v0 = __builtin_nontemporal_load(xr + s * 8);
        floatx4 v1 = __builtin_nontemporal_load(xr + s * 8 + 1);
        float vv[8] = {v0[0], v0[1], v0[2], v0[3], v1[0], v1[1], v1[2], v1[3]};
        short8 ah, al;
#pragma unroll
        for (int j = 0; j < 8; ++j) {
            short h = f2bf_rne(vv[j]);
            ah[j] = h;
            al[j] = f2bf_rne(vv[j] - bf2f(h));
        }
#pragma unroll
        for (int tO = 0; tO < 4; ++tO) {
            short8 wh = bh[(s * 4 + tO) * 64 + lane];
            short8 wl = bl[(s * 4 + tO) * 64 + lane];
            acc[tO] = __builtin_amdgcn_mfma_f32_16x16x32_bf16(ah, wh, acc[tO], 0, 0, 0);
            acc[tO] = __builtin_amdgcn_mfma_f32_16x16x32_bf16(al, wh, acc[tO], 0, 0, 0);
            acc[tO] = __builtin_amdgcn_mfma_f32_16x16x32_bf16(ah, wl, acc[tO], 0, 0, 0);
        }
    }

#pragma unroll
    for (int tO = 0; tO < 4; ++tO) {
        float bias = b[16 * tO + m];
#pragma unroll
        for (int r = 0; r < 4; ++r) {
            obf[(size_t)(node0 + q * 4 + r) * OUT_F + 16 * tO + m] =
                (unsigned short)f2bf_rne(acc[tO][r] + bias);
        }
    }
}

// ---------------- SpMM gather core: sum_e w[e]*in_bf16[src[e]][lane], f32 accumulate -----
// Padded deg distribution: {8: 2%, 16: 53%, 24: 43%, >=32: 1.5%}. Single-shot gather paths
// for 8/16/24; generic 16-loop otherwise. Edge loads as intx4 (2 edges / 16B instr).
// Gather = 2B/lane (128B/wave, lane-contiguous bf16 row).
#define GATHER_Q(NB)                                                                     \
    {                                                                                    \
        intx4 Q[NB];                                                                     \
        float v[2 * NB];                                                                 \
        _Pragma("unroll") for (int j = 0; j < NB; ++j)                                   \
            Q[j] = __builtin_nontemporal_load(eq + j);                                   \
        _Pragma("unroll") for (int j = 0; j < NB; ++j) {                                 \
            v[2 * j]     = bfu2f(in[(size_t)Q[j][0] * OUT_F + lane]);                    \
            v[2 * j + 1] = bfu2f(in[(size_t)Q[j][2] * OUT_F + lane]);                    \
        }                                                                                \
        _Pragma("unroll") for (int j = 0; j < NB; ++j) {                                 \
            acc = fmaf(__int_as_float(Q[j][1]), v[2 * j], acc);                          \
            acc = fmaf(__int_as_float(Q[j][3]), v[2 * j + 1], acc);                      \
        }                                                                                \
    }

static __device__ __forceinline__ float spmm_node(const int2* __restrict__ edges,
                                                  const unsigned short* __restrict__ in,
                                                  int lane, int e, int end) {
    float acc = 0.f;
    int deg = end - e;
    const intx4* eq = (const intx4*)(edges + e);
    if (deg == 16) {
        GATHER_Q(8)
    } else if (deg == 24) {
        GATHER_Q(12)
    } else if (deg == 8) {
        GATHER_Q(4)
    } else {
        while (e + 16 <= end) {
            GATHER_Q(8)
            e += 16;
            eq = (const intx4*)(edges + e);
        }
        if (e < end) {   // exactly 8 remain (padded to multiple of 8)
            GATHER_Q(4)
        }
    }
    return acc;
}

// OUT_BF=true: hop1/2, store bf16 rows. OUT_BF=false: final hop, store f32 to d_out.
template <bool OUT_BF>
__global__ __launch_bounds__(256) void spmm_kernel(const int2* __restrict__ bego,
                                                   const int2* __restrict__ edges,
                                                   const unsigned short* __restrict__ in,
                                                   void* __restrict__ outp, int N) {
    int gid = blockIdx.x * blockDim.x + threadIdx.x;
    int node = __builtin_amdgcn_readfirstlane(gid >> 6);
    int lane = threadIdx.x & 63;
    if (node >= N) return;
    int2 be = bego[node];            // wave-uniform -> one s_load_dwordx2
    float acc = spmm_node(edges, in, lane, be.x, be.y);
    if (OUT_BF) {
        unsigned short r = (unsigned short)f2bf_rne(acc);
        __builtin_nontemporal_store(r, (unsigned short*)outp + (size_t)node * OUT_F + lane);
    } else {
        __builtin_nontemporal_store(acc, (float*)outp + (size_t)node * OUT_F + lane);
    }
}

// ---------------- launch ----------------
extern "C" void kernel_launch(void* const* d_in, const int* in_sizes, int n_in,
                              void* d_out, int out_size, void* d_ws, size_t ws_size,
                              hipStream_t stream) {
    const float* x = (const float*)d_in[0];
    const float* W = (const float*)d_in[1];
    const float* b = (const float*)d_in[2];
    const int* esrc = (const int*)d_in[3];
    const int* edst = (const int*)d_in[4];
    const float* ew = (const float*)d_in[5];
    float* out = (float*)d_out;

    int N = in_sizes[0] / IN_F;
    int E = in_sizes[3];
    int nbkt = (N + BKT_NODES - 1) >> BKT_BITS;   // 391 for N=100000 (must be <= 512)

    char* ws = (char*)d_ws;
    size_t off = 0;
    unsigned short* bufA = (unsigned short*)(ws + off);  off += (size_t)N * OUT_F * 2;  // 12.8MB
    unsigned short* bufB = (unsigned short*)(ws + off);  off += (size_t)N * OUT_F * 2;  // 12.8MB
    int2* edges = (int2*)(ws + off);     off += (size_t)nbkt * BKT_CAP * sizeof(int2);
    int2* bego = (int2*)(ws + off);      off += (size_t)N * sizeof(int2);
    int* bkt_cnt = (int*)(ws + off);     off += 1024 * sizeof(int);
    short* bh = (short*)(ws + off);      off += 32 * 64 * 8 * sizeof(short);
    short* bl = (short*)(ws + off);      off += 32 * 64 * 8 * sizeof(short);
    // binned (391*6656*8B = 20.8MB) aliases the bufA+bufB region (25.6MB): bufA/bufB are
    // only written from gemm onward, after build_bucket_kernel consumed binned.
    int2* binned = (int2*)bufA;
    (void)ws_size; (void)n_in; (void)out_size;

    int nb_chunk = (E + CHUNK - 1) / CHUNK;   // 782 blocks

    // prep (W frags + zero) and CSR build
    prep_kernel<<<10, 256, 0, stream>>>(W, bh, bl, bkt_cnt, nbkt);
    bin_kernel<<<nb_chunk, 256, 0, stream>>>(esrc, edst, ew, bkt_cnt, binned, E, nbkt);
    build_bucket_kernel<<<nbkt, 256, 0, stream>>>(binned, bkt_cnt, bego, edges, N);

    // projection -> bf16 rows
    gemm_kernel<<<(N + 63) / 64, 256, 0, stream>>>(x, (const short8*)bh, (const short8*)bl,
                                                   b, bufA, N);

    // 3 hops: bufA -> bufB -> bufA -> out(f32)
    int spmm_blocks = (N * 64 + 255) / 256;
    spmm_kernel<true><<<spmm_blocks, 256, 0, stream>>>(bego, edges, bufA, bufB, N);
    spmm_kernel<true><<<spmm_blocks, 256, 0, stream>>>(bego, edges, bufB, bufA, N);
    spmm_kernel<false><<<spmm_blocks, 256, 0, stream>>>(bego, edges, bufA, out, N);
}

// Round 9
// 325.606 us; speedup vs baseline: 2.0962x; 1.0699x over previous
//
#include <hip/hip_runtime.h>

#define IN_F 256
#define OUT_F 64
#define BKT_BITS 8           // 256 nodes per bucket
#define BKT_NODES 256
#define BKT_CAP 6656         // mean padded 4992, sigma ~64 -> huge margin
#define SRC_BITS 18          // N < 262144
#define SRC_MASK 0x3FFFF
#define BIN_BLOCKS 256       // 1 block/CU, 1024 threads = 16 waves/CU

typedef __attribute__((ext_vector_type(8))) short short8;    // 8 bf16 (4 VGPRs) — MFMA A/B frag
typedef __attribute__((ext_vector_type(4))) float floatx4;   // MFMA C/D frag
typedef __attribute__((ext_vector_type(4))) int intx4;       // 2 edges per 16B load

static __device__ __forceinline__ short f2bf_rne(float f) {
    unsigned u = __float_as_uint(f);
    unsigned r = (u + 0x7fffu + ((u >> 16) & 1u)) >> 16;  // round-nearest-even
    return (short)r;
}
static __device__ __forceinline__ float bf2f(short s) {
    return __uint_as_float(((unsigned)(unsigned short)s) << 16);
}
static __device__ __forceinline__ float bfu2f(unsigned short s) {
    return __uint_as_float(((unsigned)s) << 16);
}

// ---------------- CSR build, pass 1: bin into fixed-capacity dst-buckets ----------------
// 256 blocks x 1024 threads (vs R6's 782x256): 16 waves/CU, ~16-edge runs per
// (block,bucket) region (write-amp ~1.3x vs 2.4x), and 100k reservation atomics vs 306k
// (3x less cross-XCD contention on bkt_cnt lines). Bucket window still written by ONE
// block -> merges in that XCD's L2 (R1 lesson: direct global scatter loses 8x).
__global__ __launch_bounds__(1024) void bin_kernel(const int* __restrict__ src,
                                                   const int* __restrict__ dst,
                                                   const float* __restrict__ w,
                                                   int* __restrict__ bkt_cnt,
                                                   int2* __restrict__ binned, int E, int nbkt) {
    __shared__ int h[512];           // nbkt = 391 <= 512
    int t = threadIdx.x;
    if (t < 512) h[t] = 0;
    __syncthreads();
    int ce = (E + BIN_BLOCKS - 1) / BIN_BLOCKS;           // ~6250 edges per block
    int beg = blockIdx.x * ce;
    int end = min(E, beg + ce);
    for (int e = beg + t; e < end; e += 1024)
        atomicAdd(&h[__builtin_nontemporal_load(dst + e) >> BKT_BITS], 1);
    __syncthreads();
    int c = (t < 512) ? h[t] : 0;
    int r = 0;
    if (t < nbkt && c) r = atomicAdd(&bkt_cnt[t], c);
    __syncthreads();
    if (t < 512) h[t] = r;   // becomes block-local cursor (offset within bucket region)
    __syncthreads();
    for (int e = beg + t; e < end; e += 1024) {
        int d = dst[e];
        int bb = d >> BKT_BITS;
        int pos = atomicAdd(&h[bb], 1);
        binned[(size_t)bb * BKT_CAP + pos] =
            make_int2(((d & (BKT_NODES - 1)) << SRC_BITS) | src[e], __float_as_int(w[e]));
    }
}

// ---------------- CSR build, pass 2 (fused): per-bucket count + padded scan + place + pad --
// Node slot counts rounded to a multiple of 8 (pads = src 0, w 0) so spmm has no remainder.
__global__ __launch_bounds__(256) void build_bucket_kernel(const int2* __restrict__ binned,
                                                           const int* __restrict__ bkt_cnt,
                                                           int2* __restrict__ bego,
                                                           int2* __restrict__ edges,
                                                           int N) {
    __shared__ int h[BKT_NODES];   // per-node counts, then cursors
    __shared__ int ssum[256];
    int t = threadIdx.x;
    int b = blockIdx.x;
    h[t] = 0;
    __syncthreads();
    int cntb = bkt_cnt[b];
    const int2* bsrc = binned + (size_t)b * BKT_CAP;
    for (int e = t; e < cntb; e += 256) atomicAdd(&h[bsrc[e].x >> SRC_BITS], 1);
    __syncthreads();
    int c = h[t];
    int p = (c + 7) & ~7;          // padded slot count
    ssum[t] = p;
    __syncthreads();
    for (int off = 1; off < 256; off <<= 1) {
        int v = (t >= off) ? ssum[t - off] : 0;
        __syncthreads();
        ssum[t] += v;
        __syncthreads();
    }
    int base = b * BKT_CAP + (t > 0 ? ssum[t - 1] : 0);
    int node = (b << BKT_BITS) + t;
    if (node < N) bego[node] = make_int2(base, base + p);
    __syncthreads();  // all reads of h-as-counts done
    h[t] = base;
    __syncthreads();
    for (int e = t; e < cntb; e += 256) {
        int2 v = bsrc[e];
        int pos = atomicAdd(&h[v.x >> SRC_BITS], 1);
        edges[pos] = make_int2(v.x & SRC_MASK, v.y);
    }
    __syncthreads();  // cursors final: base + exact count
    for (int k = h[t]; k < base + p; ++k) edges[k] = make_int2(0, 0);
}

// ---------------- prep: W -> bf16 hi/lo MFMA B-fragments (blocks 0-7) + zero (blocks 8-9) --
__global__ void prep_kernel(const float* __restrict__ W,
                            short* __restrict__ bh, short* __restrict__ bl,
                            int* __restrict__ bkt_cnt, int nbkt) {
    int blk = blockIdx.x;
    if (blk >= 8) {
        int i = (blk - 8) * 256 + threadIdx.x;
        if (i < nbkt) bkt_cnt[i] = 0;
        return;
    }
    int t = blk * 256 + threadIdx.x;
    int combo = t >> 6;
    int lane = t & 63;
    int s = combo >> 2;
    int tO = combo & 3;
    int n = 16 * tO + (lane & 15);
    int k0 = 32 * s + (lane >> 4) * 8;
    const float* src = W + (size_t)n * IN_F + k0;
    short* dh = bh + (size_t)t * 8;
    short* dl = bl + (size_t)t * 8;
#pragma unroll
    for (int j = 0; j < 8; ++j) {
        float v = src[j];
        short h = f2bf_rne(v);
        dh[j] = h;
        dl[j] = f2bf_rne(v - bf2f(h));
    }
}

// ---------------- GEMM via MFMA bf16x3; output rows stored as bf16 (128B/row) ----------
__global__ __launch_bounds__(256) void gemm_kernel(const float* __restrict__ x,
                                                   const short8* __restrict__ bh,
                                                   const short8* __restrict__ bl,
                                                   const float* __restrict__ b,
                                                   unsigned short* __restrict__ obf, int N) {
    int lane = threadIdx.x & 63;
    int wid = threadIdx.x >> 6;
    int node0 = blockIdx.x * 64 + wid * 16;
    if (node0 >= N) return;
    if (node0 + 16 > N) node0 = N - 16;
    int m = lane & 15;
    int q = lane >> 4;

    // x is a pure 102MB stream with zero reuse: nontemporal keeps L2 for everything else
    const floatx4* xr = (const floatx4*)(x + (size_t)(node0 + m) * IN_F) + q * 2;

    floatx4 acc[4];
#pragma unroll
    for (int tO = 0; tO < 4; ++tO) acc[tO] = (floatx4){0.f, 0.f, 0.f, 0.f};

#pragma unroll
    for (int s = 0; s < 8; ++s) {
        floatx4 v0 = __builtin_nontemporal_load(xr + s * 8);
        floatx4 v1 = __builtin_nontemporal_load(xr + s * 8 + 1);
        float vv[8] = {v0[0], v0[1], v0[2], v0[3], v1[0], v1[1], v1[2], v1[3]};
        short8 ah, al;
#pragma unroll
        for (int j = 0; j < 8; ++j) {
            short h = f2bf_rne(vv[j]);
            ah[j] = h;
            al[j] = f2bf_rne(vv[j] - bf2f(h));
        }
#pragma unroll
        for (int tO = 0; tO < 4; ++tO) {
            short8 wh = bh[(s * 4 + tO) * 64 + lane];
            short8 wl = bl[(s * 4 + tO) * 64 + lane];
            acc[tO] = __builtin_amdgcn_mfma_f32_16x16x32_bf16(ah, wh, acc[tO], 0, 0, 0);
            acc[tO] = __builtin_amdgcn_mfma_f32_16x16x32_bf16(al, wh, acc[tO], 0, 0, 0);
            acc[tO] = __builtin_amdgcn_mfma_f32_16x16x32_bf16(ah, wl, acc[tO], 0, 0, 0);
        }
    }

#pragma unroll
    for (int tO = 0; tO < 4; ++tO) {
        float bias = b[16 * tO + m];
#pragma unroll
        for (int r = 0; r < 4; ++r) {
            obf[(size_t)(node0 + q * 4 + r) * OUT_F + 16 * tO + m] =
                (unsigned short)f2bf_rne(acc[tO][r] + bias);
        }
    }
}

// ---------------- SpMM gather core: sum_e w[e]*in_bf16[src[e]][lane], f32 accumulate -----
// Padded deg distribution: {8: 2%, 16: 53%, 24: 43%, >=32: 1.5%}. Single-shot gather paths
// for 8/16/24; generic 16-loop otherwise. Edge loads PLAIN (not nt): the 12.8MB edge
// stream is re-read by hops 2/3 from the same per-XCD L2 slice (~1.6MB) -> keep cached.
#define GATHER_Q(NB)                                                                     \
    {                                                                                    \
        intx4 Q[NB];                                                                     \
        float v[2 * NB];                                                                 \
        _Pragma("unroll") for (int j = 0; j < NB; ++j) Q[j] = eq[j];                     \
        _Pragma("unroll") for (int j = 0; j < NB; ++j) {                                 \
            v[2 * j]     = bfu2f(in[(size_t)Q[j][0] * OUT_F + lane]);                    \
            v[2 * j + 1] = bfu2f(in[(size_t)Q[j][2] * OUT_F + lane]);                    \
        }                                                                                \
        _Pragma("unroll") for (int j = 0; j < NB; ++j) {                                 \
            acc = fmaf(__int_as_float(Q[j][1]), v[2 * j], acc);                          \
            acc = fmaf(__int_as_float(Q[j][3]), v[2 * j + 1], acc);                      \
        }                                                                                \
    }

static __device__ __forceinline__ float spmm_node(const int2* __restrict__ edges,
                                                  const unsigned short* __restrict__ in,
                                                  int lane, int e, int end) {
    float acc = 0.f;
    int deg = end - e;
    const intx4* eq = (const intx4*)(edges + e);
    if (deg == 16) {
        GATHER_Q(8)
    } else if (deg == 24) {
        GATHER_Q(12)
    } else if (deg == 8) {
        GATHER_Q(4)
    } else {
        while (e + 16 <= end) {
            GATHER_Q(8)
            e += 16;
            eq = (const intx4*)(edges + e);
        }
        if (e < end) {   // exactly 8 remain (padded to multiple of 8)
            GATHER_Q(4)
        }
    }
    return acc;
}

// OUT_BF=true: hop1/2, store bf16 rows. OUT_BF=false: final hop, store f32 to d_out.
template <bool OUT_BF>
__global__ __launch_bounds__(256) void spmm_kernel(const int2* __restrict__ bego,
                                                   const int2* __restrict__ edges,
                                                   const unsigned short* __restrict__ in,
                                                   void* __restrict__ outp, int N) {
    int gid = blockIdx.x * blockDim.x + threadIdx.x;
    int node = __builtin_amdgcn_readfirstlane(gid >> 6);
    int lane = threadIdx.x & 63;
    if (node >= N) return;
    int2 be = bego[node];            // wave-uniform -> one s_load_dwordx2
    float acc = spmm_node(edges, in, lane, be.x, be.y);
    if (OUT_BF) {
        unsigned short r = (unsigned short)f2bf_rne(acc);
        __builtin_nontemporal_store(r, (unsigned short*)outp + (size_t)node * OUT_F + lane);
    } else {
        __builtin_nontemporal_store(acc, (float*)outp + (size_t)node * OUT_F + lane);
    }
}

// ---------------- launch ----------------
extern "C" void kernel_launch(void* const* d_in, const int* in_sizes, int n_in,
                              void* d_out, int out_size, void* d_ws, size_t ws_size,
                              hipStream_t stream) {
    const float* x = (const float*)d_in[0];
    const float* W = (const float*)d_in[1];
    const float* b = (const float*)d_in[2];
    const int* esrc = (const int*)d_in[3];
    const int* edst = (const int*)d_in[4];
    const float* ew = (const float*)d_in[5];
    float* out = (float*)d_out;

    int N = in_sizes[0] / IN_F;
    int E = in_sizes[3];
    int nbkt = (N + BKT_NODES - 1) >> BKT_BITS;   // 391 for N=100000 (must be <= 512)

    char* ws = (char*)d_ws;
    size_t off = 0;
    unsigned short* bufA = (unsigned short*)(ws + off);  off += (size_t)N * OUT_F * 2;  // 12.8MB
    unsigned short* bufB = (unsigned short*)(ws + off);  off += (size_t)N * OUT_F * 2;  // 12.8MB
    int2* edges = (int2*)(ws + off);     off += (size_t)nbkt * BKT_CAP * sizeof(int2);
    int2* bego = (int2*)(ws + off);      off += (size_t)N * sizeof(int2);
    int* bkt_cnt = (int*)(ws + off);     off += 1024 * sizeof(int);
    short* bh = (short*)(ws + off);      off += 32 * 64 * 8 * sizeof(short);
    short* bl = (short*)(ws + off);      off += 32 * 64 * 8 * sizeof(short);
    // binned (391*6656*8B = 20.8MB) aliases the bufA+bufB region (25.6MB): bufA/bufB are
    // only written from gemm onward, after build_bucket_kernel consumed binned.
    int2* binned = (int2*)bufA;
    (void)ws_size; (void)n_in; (void)out_size;

    // prep (W frags + zero) and CSR build
    prep_kernel<<<10, 256, 0, stream>>>(W, bh, bl, bkt_cnt, nbkt);
    bin_kernel<<<BIN_BLOCKS, 1024, 0, stream>>>(esrc, edst, ew, bkt_cnt, binned, E, nbkt);
    build_bucket_kernel<<<nbkt, 256, 0, stream>>>(binned, bkt_cnt, bego, edges, N);

    // projection -> bf16 rows
    gemm_kernel<<<(N + 63) / 64, 256, 0, stream>>>(x, (const short8*)bh, (const short8*)bl,
                                                   b, bufA, N);

    // 3 hops: bufA -> bufB -> bufA -> out(f32)
    int spmm_blocks = (N * 64 + 255) / 256;
    spmm_kernel<true><<<spmm_blocks, 256, 0, stream>>>(bego, edges, bufA, bufB, N);
    spmm_kernel<true><<<spmm_blocks, 256, 0, stream>>>(bego, edges, bufB, bufA, N);
    spmm_kernel<false><<<spmm_blocks, 256, 0, stream>>>(bego, edges, bufA, out, N);
}